// Round 7
// baseline (115.975 us; speedup 1.0000x reference)
//
#include <hip/hip_runtime.h>
#include <math.h>

// ---------------------------------------------------------------------------
// Problem: B=32, L=1024, C=34, PATCH=16, d=256, E=8, pred=96.
// Algebraic reductions (verified R1-R6):
//   * final [:, :, :1] slice -> only channel n=0 per batch (series x[b,:,2])
//   * flat[:, :1024] truncation -> only patches p=0..3 contribute
// => 32 series, 4 patches each, 8 expert 256x256 matvecs per (b,p), one
//    96x1024 head matvec per b.  ~0.3 GFLOP; launch/latency-bound.
//
// LESSONS: R4 - no intra-kernel cross-workgroup handoff (XCD L2 non-coherent,
//   tripwire).  R5 - redundant recompute + uncoalesced rows >> launch cost.
//   R6 - batch-tiling the Wt read works (112.2 us).
//
// R7 = R6 with deeper batch tiling:
//   k_stats : 256 blocks; transpose W_experts tiles + (blocks 0-31) stats/
//             norm/proj/router.  (R3/R6 exact)
//   k_expert: 256 blocks = (bg4, hq, e); ONE Wt slice read serves 4 batches
//             (Wt aggregate 32 MB -> 16 MB, 4 indep accumulators).
//   k_head  : 16 blocks = batch pairs; each W_head row load is dotted with
//             BOTH batches' f vectors (W_head traffic 12.6 -> 6.3 MB).
// ---------------------------------------------------------------------------

#define NB 32
#define LSEQ 1024
#define CCH 34
#define NP 4
#define DMODEL 256
#define NEXP 8
#define PRED 96

#define WT_FLOATS    (NEXP * DMODEL * DMODEL)   // 524288
#define XP_FLOATS    (NB * NP * DMODEL)         // 32768
#define GATES_FLOATS (NB * NP * NEXP)           // 1024
#define STATS_FLOATS (NB * 2)                   // 64
#define FLAT_FLOATS  (NEXP * NB * LSEQ)         // 262144 (8 partial buffers)

// ---------------------------------------------------------------------------
// Kernel A (R3/R6 exact): distributed transpose + (blocks 0-31) stats path.
// grid = 256, block = 256.  LDS tile [64][33] -> conflict-free both ways.
// ---------------------------------------------------------------------------
__global__ __launch_bounds__(256) void k_stats(
    const float* __restrict__ x,
    const float* __restrict__ W_proj, const float* __restrict__ b_proj,
    const float* __restrict__ W_router, const float* __restrict__ b_router,
    const float* __restrict__ W_experts, float* __restrict__ Wt,
    float* __restrict__ xp_ws, float* __restrict__ gates_ws,
    float* __restrict__ stats_ws)
{
    const int bid = blockIdx.x;
    const int tid = threadIdx.x;
    const int b = bid;            // batch id, valid only for bid < NB

    __shared__ float tile[64][33];
    __shared__ float xn[LSEQ];
    __shared__ float xp_s[NP * DMODEL];
    __shared__ float red[8];
    __shared__ float lg[32];
    __shared__ float mean_s, rstd_s;

    // stats blocks: issue the strided series loads FIRST (long HBM latency)
    float v[4];
    if (b < NB) {
        #pragma unroll
        for (int i = 0; i < 4; ++i)
            v[i] = x[(size_t)(b * LSEQ + tid + 256 * i) * CCH + 2];
    }

    // ---- distributed transpose: one 64(h) x 32(d) tile per block
    {
        const int e  = bid >> 5;
        const int h0 = ((bid >> 3) & 3) << 6;
        const int d0 = (bid & 7) << 5;
        const float* src = W_experts + ((size_t)e << 16);
        float*       dst = Wt        + ((size_t)e << 16);
        const int dx = tid & 31, hy = tid >> 5;   // load: 32 d-lanes x 8 h-rows
        const int hx = tid & 63, dy = tid >> 6;   // store: 64 h-lanes x 4 d-rows
        #pragma unroll
        for (int i = 0; i < 8; ++i) {
            const int hh = hy + 8 * i;
            tile[hh][dx] = src[(size_t)(h0 + hh) * DMODEL + d0 + dx];
        }
        __syncthreads();
        #pragma unroll
        for (int i = 0; i < 8; ++i) {
            const int dd = dy + 4 * i;
            dst[(size_t)(d0 + dd) * DMODEL + h0 + hx] = tile[hx][dd];
        }
    }

    if (b >= NB) return;   // transpose-only blocks done

    // ---- stats over the 1024-length series
    float s = 0.f, sq = 0.f;
    #pragma unroll
    for (int i = 0; i < 4; ++i) { s += v[i]; sq += v[i] * v[i]; }
    #pragma unroll
    for (int off = 32; off > 0; off >>= 1) {
        s  += __shfl_down(s,  off);
        sq += __shfl_down(sq, off);
    }
    const int wave = tid >> 6;
    if ((tid & 63) == 0) { red[wave * 2] = s; red[wave * 2 + 1] = sq; }
    __syncthreads();
    if (tid == 0) {
        const float S = red[0] + red[2] + red[4] + red[6];
        const float Q = red[1] + red[3] + red[5] + red[7];
        const float mean = S * (1.0f / LSEQ);
        const float var  = Q * (1.0f / LSEQ) - mean * mean;
        const float stdv = sqrtf(var + 1e-5f);
        mean_s = mean;
        rstd_s = 1.0f / stdv;
        stats_ws[b * 2]     = mean;
        stats_ws[b * 2 + 1] = stdv;
    }
    __syncthreads();
    const float mean = mean_s, rstd = rstd_s;
    #pragma unroll
    for (int i = 0; i < 4; ++i)
        xn[tid + 256 * i] = (v[i] - mean) * rstd;
    __syncthreads();

    // ---- patch projection: xp[p][h], thread h
    {
        const int h = tid;
        float wrow[16];
        #pragma unroll
        for (int j = 0; j < 16; ++j) wrow[j] = W_proj[h * 16 + j];
        const float bp = b_proj[h];
        #pragma unroll
        for (int p = 0; p < NP; ++p) {
            float acc = bp;
            #pragma unroll
            for (int j = 0; j < 16; ++j) acc += xn[p * 16 + j] * wrow[j];
            xp_s[p * DMODEL + h] = acc;
            xp_ws[((size_t)b * NP + p) * DMODEL + h] = acc;
        }
    }
    __syncthreads();

    // ---- router logits (threads 0..31 -> (p,e))
    if (tid < 32) {
        const int p = tid >> 3, e = tid & 7;
        float acc = b_router[e];
        const float* wr = W_router + e * DMODEL;
        const float* xp = xp_s + p * DMODEL;
        #pragma unroll 8
        for (int h = 0; h < DMODEL; ++h) acc += xp[h] * wr[h];
        lg[tid] = acc;
    }
    __syncthreads();

    // ---- softmax over 8 experts (threads 0..3 -> p)
    if (tid < NP) {
        const int p = tid;
        float m = -1e30f;
        #pragma unroll
        for (int e = 0; e < NEXP; ++e) m = fmaxf(m, lg[p * 8 + e]);
        float ex[NEXP];
        float sum = 0.f;
        #pragma unroll
        for (int e = 0; e < NEXP; ++e) { ex[e] = expf(lg[p * 8 + e] - m); sum += ex[e]; }
        const float inv = 1.0f / sum;
        #pragma unroll
        for (int e = 0; e < NEXP; ++e)
            gates_ws[((size_t)b * NP + p) * NEXP + e] = ex[e] * inv;
    }
}

// ---------------------------------------------------------------------------
// Kernel B: 4-batch-tiled expert matvecs.
// grid = 256: bid -> (bg4 = bid>>5 [8 quads], hq = (bid>>3)&3, e = bid&7);
// block = 256: tid -> (p = tid>>6, hl = tid&63), h = hq*64+hl.
// One Wt column-slice read (64 KB) serves 4 batches x 4 patches:
//   Wt loads 256B lane-coalesced, L1 reuse across the 4 p-waves,
//   4 independent accumulators/thread, xp broadcast from LDS (16 KB).
// Disjoint flat_part writes -> deterministic, no init, no atomics.
// ---------------------------------------------------------------------------
__global__ __launch_bounds__(256) void k_expert(
    const float* __restrict__ Wt, const float* __restrict__ b_experts,
    const float* __restrict__ xp_ws, const float* __restrict__ gates_ws,
    float* __restrict__ flat_part)
{
    const int bid = blockIdx.x;
    const int bg4 = bid >> 5;           // batch quad 0..7
    const int r   = bid & 31;
    const int hq  = r >> 3;
    const int e   = r & 7;
    const int b0  = bg4 * 4;
    const int tid = threadIdx.x;
    const int p   = tid >> 6;
    const int hl  = tid & 63;
    const int h   = (hq << 6) + hl;

    __shared__ float xp_s[4 * NP * DMODEL];   // [i][p][256], 16 KB
    __shared__ float g_s[4 * NP * NEXP];      // [i][p][8]

    // stage xp for 4 batches (4096 consecutive floats), coalesced float4
    {
        const float4* src = (const float4*)(xp_ws + ((size_t)b0 << 10));
        float4* dst = (float4*)xp_s;
        #pragma unroll
        for (int i = 0; i < 4; ++i)
            dst[tid + 256 * i] = src[tid + 256 * i];
    }
    if (tid < 128) g_s[tid] = gates_ws[(size_t)b0 * (NP * NEXP) + tid];
    __syncthreads();

    const float* wt  = Wt + ((size_t)e << 16) + h;
    const float bias = b_experts[(e << 8) + h];
    const float4* xp0 = (const float4*)(xp_s + ((0 * NP + p) << 8));
    const float4* xp1 = (const float4*)(xp_s + ((1 * NP + p) << 8));
    const float4* xp2 = (const float4*)(xp_s + ((2 * NP + p) << 8));
    const float4* xp3 = (const float4*)(xp_s + ((3 * NP + p) << 8));

    float a0 = 0.f, a1 = 0.f, a2 = 0.f, a3 = 0.f;
    #pragma unroll 4
    for (int q = 0; q < DMODEL / 4; ++q) {
        const float w0 = wt[(size_t)(4 * q + 0) << 8];
        const float w1 = wt[(size_t)(4 * q + 1) << 8];
        const float w2 = wt[(size_t)(4 * q + 2) << 8];
        const float w3 = wt[(size_t)(4 * q + 3) << 8];
        const float4 xA = xp0[q];
        const float4 xB = xp1[q];
        const float4 xC = xp2[q];
        const float4 xD = xp3[q];
        a0 += w0 * xA.x + w1 * xA.y + w2 * xA.z + w3 * xA.w;
        a1 += w0 * xB.x + w1 * xB.y + w2 * xB.z + w3 * xB.w;
        a2 += w0 * xC.x + w1 * xC.y + w2 * xC.z + w3 * xC.w;
        a3 += w0 * xD.x + w1 * xD.y + w2 * xD.z + w3 * xD.w;
    }

    const size_t base = ((size_t)e * NB + b0) << 10;
    const int    off  = (p << 8) + h;
    flat_part[base              + off] = g_s[(0 << 5) + (p << 3) + e] * (a0 + bias);
    flat_part[base + (1 << 10)  + off] = g_s[(1 << 5) + (p << 3) + e] * (a1 + bias);
    flat_part[base + (2 << 10)  + off] = g_s[(2 << 5) + (p << 3) + e] * (a2 + bias);
    flat_part[base + (3 << 10)  + off] = g_s[(3 << 5) + (p << 3) + e] * (a3 + bias);
}

// ---------------------------------------------------------------------------
// Kernel C: batch-pair head.  grid = 16 (batch pairs), block = 256 (4 waves).
// Stage both batches' f vectors (sum partials + un-normalize) in LDS, pull
// to registers, then each W_head row float4 load feeds BOTH batch dots.
// ---------------------------------------------------------------------------
__global__ __launch_bounds__(256) void k_head(
    const float* __restrict__ flat_part, const float* __restrict__ stats_ws,
    const float* __restrict__ W_head, const float* __restrict__ b_head,
    float* __restrict__ out)
{
    const int bp  = blockIdx.x;         // batch pair
    const int b0  = bp * 2;
    const int tid = threadIdx.x;
    __shared__ float4 f4s[2 * DMODEL];  // two 1024-float vectors

    // stage both batches: f[i][l] = (sum_e part[e][b0+i][l]) * std + mean
    #pragma unroll
    for (int i = 0; i < 2; ++i) {
        const int b = b0 + i;
        const float mean = stats_ws[b * 2];
        const float stdv = stats_ws[b * 2 + 1];
        float4 acc = make_float4(0.f, 0.f, 0.f, 0.f);
        #pragma unroll
        for (int e = 0; e < NEXP; ++e) {
            const float4 t = ((const float4*)(flat_part + (((size_t)e * NB + b) << 10)))[tid];
            acc.x += t.x; acc.y += t.y; acc.z += t.z; acc.w += t.w;
        }
        acc.x = acc.x * stdv + mean;
        acc.y = acc.y * stdv + mean;
        acc.z = acc.z * stdv + mean;
        acc.w = acc.w * stdv + mean;
        f4s[(i << 8) + tid] = acc;
    }
    __syncthreads();

    const int lane = tid & 63;
    const int w    = tid >> 6;
    float4 fr0[4], fr1[4];
    #pragma unroll
    for (int c = 0; c < 4; ++c) {
        fr0[c] = f4s[lane + 64 * c];
        fr1[c] = f4s[256 + lane + 64 * c];
    }

    #pragma unroll 2
    for (int i = 0; i < PRED / 4; ++i) {
        const int k = w + 4 * i;
        const float4* wr = (const float4*)(W_head + (size_t)k * LSEQ);
        float a0 = 0.f, a1 = 0.f;
        #pragma unroll
        for (int c = 0; c < 4; ++c) {
            const float4 t = wr[lane + 64 * c];
            a0 += t.x * fr0[c].x + t.y * fr0[c].y + t.z * fr0[c].z + t.w * fr0[c].w;
            a1 += t.x * fr1[c].x + t.y * fr1[c].y + t.z * fr1[c].z + t.w * fr1[c].w;
        }
        #pragma unroll
        for (int off = 32; off > 0; off >>= 1) {
            a0 += __shfl_xor(a0, off);
            a1 += __shfl_xor(a1, off);
        }
        if (lane == 0) {
            const float bh = b_head[k];
            out[(size_t)b0 * PRED + k]        = bh + a0;
            out[(size_t)(b0 + 1) * PRED + k]  = bh + a1;
        }
    }
}

// ---------------------------------------------------------------------------
extern "C" void kernel_launch(void* const* d_in, const int* in_sizes, int n_in,
                              void* d_out, int out_size, void* d_ws, size_t ws_size,
                              hipStream_t stream)
{
    const float* x         = (const float*)d_in[0];
    const float* W_proj    = (const float*)d_in[4];
    const float* b_proj    = (const float*)d_in[5];
    const float* W_router  = (const float*)d_in[6];
    const float* b_router  = (const float*)d_in[7];
    const float* W_experts = (const float*)d_in[8];
    const float* b_experts = (const float*)d_in[9];
    const float* W_head    = (const float*)d_in[10];
    const float* b_head    = (const float*)d_in[11];
    float* out = (float*)d_out;
    float* ws  = (float*)d_ws;

    float* Wt        = ws;
    float* xp_ws     = ws + WT_FLOATS;
    float* gates_ws  = xp_ws + XP_FLOATS;
    float* stats_ws  = gates_ws + GATES_FLOATS;
    float* flat_part = stats_ws + STATS_FLOATS;

    k_stats<<<256, 256, 0, stream>>>(x, W_proj, b_proj, W_router, b_router,
                                     W_experts, Wt, xp_ws, gates_ws, stats_ws);
    k_expert<<<256, 256, 0, stream>>>(Wt, b_experts, xp_ws, gates_ws, flat_part);
    k_head<<<16, 256, 0, stream>>>(flat_part, stats_ws, W_head, b_head, out);
}

// Round 8
// 110.842 us; speedup vs baseline: 1.0463x; 1.0463x over previous
//
#include <hip/hip_runtime.h>
#include <math.h>

// ---------------------------------------------------------------------------
// Problem: B=32, L=1024, C=34, PATCH=16, d=256, E=8, pred=96.
// Algebraic reductions (verified R1-R7):
//   * final [:, :, :1] slice -> only channel n=0 per batch (series x[b,:,2])
//   * flat[:, :1024] truncation -> only patches p=0..3 contribute
// => 32 series, 4 patches each, 8 expert 256x256 matvecs per (b,p), one
//    96x1024 head matvec per b.  ~0.3 GFLOP; launch/latency-bound.
//
// LESSONS: R4 - no intra-kernel cross-workgroup handoff (XCD L2 non-coherent,
//   tripwire).  R5 - redundant recompute + uncoalesced rows >> launch cost.
//   R6 - 2-batch Wt tiling at 2 blocks/CU = optimum (112.2 us).
//   R7 - 4-batch tiling at 1 block/CU regressed (occupancy > traffic here).
//
// R8 = R6 verbatim (proven best):
//   k_stats : 256 blocks; all transpose one 64x32 tile of W_experts,
//             blocks 0-31 additionally do stats/norm/proj/router.
//   k_expert: 512 blocks = (bg2, hq, e), each serves 2 batches from ONE
//             Wt slice read.
//   k_head  : 32 blocks; partial-sum + un-normalize + head matvec.
// ---------------------------------------------------------------------------

#define NB 32
#define LSEQ 1024
#define CCH 34
#define NP 4
#define DMODEL 256
#define NEXP 8
#define PRED 96

#define WT_FLOATS    (NEXP * DMODEL * DMODEL)   // 524288
#define XP_FLOATS    (NB * NP * DMODEL)         // 32768
#define GATES_FLOATS (NB * NP * NEXP)           // 1024
#define STATS_FLOATS (NB * 2)                   // 64
#define FLAT_FLOATS  (NEXP * NB * LSEQ)         // 262144 (8 partial buffers)

// ---------------------------------------------------------------------------
// Kernel A: distributed transpose + (blocks 0-31) stats path.
// grid = 256, block = 256.  LDS tile [64][33] -> conflict-free both ways.
// ---------------------------------------------------------------------------
__global__ __launch_bounds__(256) void k_stats(
    const float* __restrict__ x,
    const float* __restrict__ W_proj, const float* __restrict__ b_proj,
    const float* __restrict__ W_router, const float* __restrict__ b_router,
    const float* __restrict__ W_experts, float* __restrict__ Wt,
    float* __restrict__ xp_ws, float* __restrict__ gates_ws,
    float* __restrict__ stats_ws)
{
    const int bid = blockIdx.x;
    const int tid = threadIdx.x;
    const int b = bid;            // batch id, valid only for bid < NB

    __shared__ float tile[64][33];
    __shared__ float xn[LSEQ];
    __shared__ float xp_s[NP * DMODEL];
    __shared__ float red[8];
    __shared__ float lg[32];
    __shared__ float mean_s, rstd_s;

    // stats blocks: issue the strided series loads FIRST (long HBM latency)
    float v[4];
    if (b < NB) {
        #pragma unroll
        for (int i = 0; i < 4; ++i)
            v[i] = x[(size_t)(b * LSEQ + tid + 256 * i) * CCH + 2];
    }

    // ---- distributed transpose: one 64(h) x 32(d) tile per block
    {
        const int e  = bid >> 5;
        const int h0 = ((bid >> 3) & 3) << 6;
        const int d0 = (bid & 7) << 5;
        const float* src = W_experts + ((size_t)e << 16);
        float*       dst = Wt        + ((size_t)e << 16);
        const int dx = tid & 31, hy = tid >> 5;   // load: 32 d-lanes x 8 h-rows
        const int hx = tid & 63, dy = tid >> 6;   // store: 64 h-lanes x 4 d-rows
        #pragma unroll
        for (int i = 0; i < 8; ++i) {
            const int hh = hy + 8 * i;
            tile[hh][dx] = src[(size_t)(h0 + hh) * DMODEL + d0 + dx];
        }
        __syncthreads();
        #pragma unroll
        for (int i = 0; i < 8; ++i) {
            const int dd = dy + 4 * i;
            dst[(size_t)(d0 + dd) * DMODEL + h0 + hx] = tile[hx][dd];
        }
    }

    if (b >= NB) return;   // transpose-only blocks done

    // ---- stats over the 1024-length series
    float s = 0.f, sq = 0.f;
    #pragma unroll
    for (int i = 0; i < 4; ++i) { s += v[i]; sq += v[i] * v[i]; }
    #pragma unroll
    for (int off = 32; off > 0; off >>= 1) {
        s  += __shfl_down(s,  off);
        sq += __shfl_down(sq, off);
    }
    const int wave = tid >> 6;
    if ((tid & 63) == 0) { red[wave * 2] = s; red[wave * 2 + 1] = sq; }
    __syncthreads();
    if (tid == 0) {
        const float S = red[0] + red[2] + red[4] + red[6];
        const float Q = red[1] + red[3] + red[5] + red[7];
        const float mean = S * (1.0f / LSEQ);
        const float var  = Q * (1.0f / LSEQ) - mean * mean;
        const float stdv = sqrtf(var + 1e-5f);
        mean_s = mean;
        rstd_s = 1.0f / stdv;
        stats_ws[b * 2]     = mean;
        stats_ws[b * 2 + 1] = stdv;
    }
    __syncthreads();
    const float mean = mean_s, rstd = rstd_s;
    #pragma unroll
    for (int i = 0; i < 4; ++i)
        xn[tid + 256 * i] = (v[i] - mean) * rstd;
    __syncthreads();

    // ---- patch projection: xp[p][h], thread h
    {
        const int h = tid;
        float wrow[16];
        #pragma unroll
        for (int j = 0; j < 16; ++j) wrow[j] = W_proj[h * 16 + j];
        const float bp = b_proj[h];
        #pragma unroll
        for (int p = 0; p < NP; ++p) {
            float acc = bp;
            #pragma unroll
            for (int j = 0; j < 16; ++j) acc += xn[p * 16 + j] * wrow[j];
            xp_s[p * DMODEL + h] = acc;
            xp_ws[((size_t)b * NP + p) * DMODEL + h] = acc;
        }
    }
    __syncthreads();

    // ---- router logits (threads 0..31 -> (p,e))
    if (tid < 32) {
        const int p = tid >> 3, e = tid & 7;
        float acc = b_router[e];
        const float* wr = W_router + e * DMODEL;
        const float* xp = xp_s + p * DMODEL;
        #pragma unroll 8
        for (int h = 0; h < DMODEL; ++h) acc += xp[h] * wr[h];
        lg[tid] = acc;
    }
    __syncthreads();

    // ---- softmax over 8 experts (threads 0..3 -> p)
    if (tid < NP) {
        const int p = tid;
        float m = -1e30f;
        #pragma unroll
        for (int e = 0; e < NEXP; ++e) m = fmaxf(m, lg[p * 8 + e]);
        float ex[NEXP];
        float sum = 0.f;
        #pragma unroll
        for (int e = 0; e < NEXP; ++e) { ex[e] = expf(lg[p * 8 + e] - m); sum += ex[e]; }
        const float inv = 1.0f / sum;
        #pragma unroll
        for (int e = 0; e < NEXP; ++e)
            gates_ws[((size_t)b * NP + p) * NEXP + e] = ex[e] * inv;
    }
}

// ---------------------------------------------------------------------------
// Kernel B: batch-tiled expert matvecs.
// grid = 512: bid -> (bg2 = bid>>5 [16 pairs], hq = (bid>>3)&3, e = bid&7);
// block = 256: tid -> (p = tid>>6, hl = tid&63), h = hq*64+hl.
// One Wt column-slice read (64 KB) serves 2 batches x 4 patches:
//   Wt loads 256B lane-coalesced, L1 reuse across the 4 p-waves,
//   2 accumulators/thread (ILP), LDS xp broadcast via ds_read_b128.
// Disjoint flat_part writes -> deterministic, no init, no atomics.
// ---------------------------------------------------------------------------
__global__ __launch_bounds__(256) void k_expert(
    const float* __restrict__ Wt, const float* __restrict__ b_experts,
    const float* __restrict__ xp_ws, const float* __restrict__ gates_ws,
    float* __restrict__ flat_part)
{
    const int bid = blockIdx.x;
    const int bg2 = bid >> 5;           // batch pair 0..15
    const int r   = bid & 31;
    const int hq  = r >> 3;
    const int e   = r & 7;
    const int b0  = bg2 * 2;
    const int tid = threadIdx.x;
    const int p   = tid >> 6;
    const int hl  = tid & 63;
    const int h   = (hq << 6) + hl;

    __shared__ float xp_s[2 * NP * DMODEL];   // [i][p][256], 8 KB
    __shared__ float g_s[2 * NP * NEXP];      // [i][p][8]

    // stage xp for both batches (2048 consecutive floats), coalesced float4
    {
        const float4* src = (const float4*)(xp_ws + ((size_t)b0 << 10));
        float4* dst = (float4*)xp_s;
        dst[tid]       = src[tid];
        dst[tid + 256] = src[tid + 256];
    }
    if (tid < 64) g_s[tid] = gates_ws[(size_t)b0 * (NP * NEXP) + tid];
    __syncthreads();

    const float* wt  = Wt + ((size_t)e << 16) + h;
    const float bias = b_experts[(e << 8) + h];
    const float4* xpA = (const float4*)(xp_s + (p << 8));            // batch b0
    const float4* xpB = (const float4*)(xp_s + ((4 + p) << 8));      // batch b0+1

    float a0 = 0.f, a1 = 0.f;
    #pragma unroll 4
    for (int q = 0; q < DMODEL / 4; ++q) {
        const float w0 = wt[(size_t)(4 * q + 0) << 8];
        const float w1 = wt[(size_t)(4 * q + 1) << 8];
        const float w2 = wt[(size_t)(4 * q + 2) << 8];
        const float w3 = wt[(size_t)(4 * q + 3) << 8];
        const float4 xA = xpA[q];
        const float4 xB = xpB[q];
        a0 += w0 * xA.x + w1 * xA.y + w2 * xA.z + w3 * xA.w;
        a1 += w0 * xB.x + w1 * xB.y + w2 * xB.z + w3 * xB.w;
    }

    const float g0 = g_s[(p << 3) + e];
    const float g1 = g_s[32 + (p << 3) + e];
    flat_part[(((size_t)e * NB + b0)     << 10) + (p << 8) + h] = g0 * (a0 + bias);
    flat_part[(((size_t)e * NB + b0 + 1) << 10) + (p << 8) + h] = g1 * (a1 + bias);
}

// ---------------------------------------------------------------------------
// Kernel C: sum 8 partials, un-normalize, head matvec.
// grid = 32, block = 256 (4 waves).
// ---------------------------------------------------------------------------
__global__ __launch_bounds__(256) void k_head(
    const float* __restrict__ flat_part, const float* __restrict__ stats_ws,
    const float* __restrict__ W_head, const float* __restrict__ b_head,
    float* __restrict__ out)
{
    const int b = blockIdx.x;
    const int tid = threadIdx.x;
    __shared__ float4 f4s[DMODEL];   // 1024 floats

    const float mean = stats_ws[b * 2];
    const float stdv = stats_ws[b * 2 + 1];

    // stage: f[l] = (sum_e part[e][b][l]) * std + mean   (fixed e-order)
    {
        float4 acc = make_float4(0.f, 0.f, 0.f, 0.f);
        #pragma unroll
        for (int e = 0; e < NEXP; ++e) {
            const float4 t = ((const float4*)(flat_part + (((size_t)e * NB + b) << 10)))[tid];
            acc.x += t.x; acc.y += t.y; acc.z += t.z; acc.w += t.w;
        }
        acc.x = acc.x * stdv + mean;
        acc.y = acc.y * stdv + mean;
        acc.z = acc.z * stdv + mean;
        acc.w = acc.w * stdv + mean;
        f4s[tid] = acc;
    }
    __syncthreads();

    const int lane = tid & 63;
    const int w    = tid >> 6;
    float4 fr[4];
    #pragma unroll
    for (int c = 0; c < 4; ++c) fr[c] = f4s[lane + 64 * c];

    #pragma unroll 2
    for (int i = 0; i < PRED / 4; ++i) {
        const int k = w + 4 * i;
        const float4* wr = (const float4*)(W_head + (size_t)k * LSEQ);
        float a = 0.f;
        #pragma unroll
        for (int c = 0; c < 4; ++c) {
            const float4 t = wr[lane + 64 * c];
            a += t.x * fr[c].x + t.y * fr[c].y + t.z * fr[c].z + t.w * fr[c].w;
        }
        #pragma unroll
        for (int off = 32; off > 0; off >>= 1)
            a += __shfl_xor(a, off);
        if (lane == 0)
            out[(size_t)b * PRED + k] = b_head[k] + a;
    }
}

// ---------------------------------------------------------------------------
extern "C" void kernel_launch(void* const* d_in, const int* in_sizes, int n_in,
                              void* d_out, int out_size, void* d_ws, size_t ws_size,
                              hipStream_t stream)
{
    const float* x         = (const float*)d_in[0];
    const float* W_proj    = (const float*)d_in[4];
    const float* b_proj    = (const float*)d_in[5];
    const float* W_router  = (const float*)d_in[6];
    const float* b_router  = (const float*)d_in[7];
    const float* W_experts = (const float*)d_in[8];
    const float* b_experts = (const float*)d_in[9];
    const float* W_head    = (const float*)d_in[10];
    const float* b_head    = (const float*)d_in[11];
    float* out = (float*)d_out;
    float* ws  = (float*)d_ws;

    float* Wt        = ws;
    float* xp_ws     = ws + WT_FLOATS;
    float* gates_ws  = xp_ws + XP_FLOATS;
    float* stats_ws  = gates_ws + GATES_FLOATS;
    float* flat_part = stats_ws + STATS_FLOATS;

    k_stats<<<256, 256, 0, stream>>>(x, W_proj, b_proj, W_router, b_router,
                                     W_experts, Wt, xp_ws, gates_ws, stats_ws);
    k_expert<<<512, 256, 0, stream>>>(Wt, b_experts, xp_ws, gates_ws, flat_part);
    k_head<<<NB, 256, 0, stream>>>(flat_part, stats_ws, W_head, b_head, out);
}